// Round 15
// baseline (149.036 us; speedup 1.0000x reference)
//
#include <hip/hip_runtime.h>
#include <math.h>

#define B 8
#define V 1024
#define E 32
#define H 4
#define CAP 64        // max out-degree capacity; E[deg]=17, P(deg>64) ~ 1e-21
#define MAXNNZ 20480  // nnz ~ 17390 +/- 128; +24 sigma headroom
#define SE (MAXNNZ / V)  // 20 edges per thread in flow kernel
#define ZBLK 128      // zero-role blocks in setup kernel

// XCD-aware decode: blockIdx round-robins across 8 XCDs on MI355X, and B==8.
// b = blockIdx & 7 pins each batch to one XCD -> per-XCD working set fits 4MB L2.

__device__ __forceinline__ float wave_sum(float v) {
  for (int o = 32; o > 0; o >>= 1) v += __shfl_xor(v, o);
  return v;
}
__device__ __forceinline__ float wave_max(float v) {
  for (int o = 32; o > 0; o >>= 1) v = fmaxf(v, __shfl_xor(v, o));
  return v;
}

// ---- L0: zero deg_in/slot_cur/done + precompute wa1/wa2 = gat_w @ a1/a2 ----
__global__ void zero_wa_kernel(int* __restrict__ deg_in, int* __restrict__ slot_cur,
                               unsigned* __restrict__ done, const float* __restrict__ gat_w,
                               const float* __restrict__ a1, const float* __restrict__ a2,
                               float* __restrict__ wa1, float* __restrict__ wa2) {
  int blk = blockIdx.x, tid = threadIdx.x;
  if (blk < 4) {
    deg_in[blk * 256 + tid] = 0;
  } else if (blk < 8) {
    slot_cur[(blk - 4) * 256 + tid] = 0;
  } else {
    if (tid == 0) *done = 0u;
    int h = tid >> 6, f = tid & 63;
    float s1 = 0.f, s2 = 0.f;
    const float* W = gat_w + h * 4096 + f * 64;
    for (int g = 0; g < 64; ++g) {
      float w = W[g];
      s1 += w * a1[h * 64 + g];
      s2 += w * a2[h * 64 + g];
    }
    wa1[h * 64 + f] = s1;
    wa2[h * 64 + f] = s2;
  }
}

// ---- L1: merged setup (64-thread blocks, role by blockIdx) ----
#define ENV 8
__global__ void setup_kernel(const float* __restrict__ adj, const float* __restrict__ demands,
                             const float* __restrict__ emb,
                             const float* __restrict__ ew1, const float* __restrict__ eb1,
                             const float* __restrict__ ew2, const float* __restrict__ eb2,
                             const float* __restrict__ dec_w2,
                             const float* __restrict__ wa1, const float* __restrict__ wa2,
                             int* __restrict__ nbr, int* __restrict__ deg,
                             int* __restrict__ deg_in, float* __restrict__ enc,
                             float* __restrict__ ss, float* __restrict__ sn,
                             float* __restrict__ w2t, float* __restrict__ fwe,
                             unsigned int* __restrict__ meta) {
  int blk = blockIdx.x;
  int j = threadIdx.x;  // 64
  if (blk < V) {
    int v = blk;
    int base = 0;
    for (int c = 0; c < V; c += 64) {
      float a = adj[v * V + c + j];
      unsigned long long m = __ballot(a > 0.5f);
      int pos = __popcll(m & ((1ull << j) - 1ull));
      if (a > 0.5f && base + pos < CAP) {
        nbr[v * CAP + base + pos] = c + j;
        atomicAdd(&deg_in[c + j], 1);
      }
      base += __popcll(m);
    }
    if (j == 0) deg[v] = (base < CAP) ? base : CAP;
  } else if (blk < 2 * V) {
    int eb = blk - V;
    int b = eb & 7;
    int v0 = (eb >> 3) * ENV;
    int bv0 = b * V + v0;
    __shared__ float xs[ENV][E + 1];
    __shared__ float hs[ENV][64];
#pragma unroll
    for (int n = 0; n < ENV; ++n) {
      if (j < E) xs[n][j] = emb[(v0 + n) * E + j];
      else if (j == E) xs[n][E] = demands[b * V + v0 + n];
    }
    __syncthreads();
    float h[ENV];
#pragma unroll
    for (int n = 0; n < ENV; ++n) h[n] = eb1[j];
    for (int i = 0; i < E + 1; ++i) {
      float wv = ew1[i * 64 + j];
#pragma unroll
      for (int n = 0; n < ENV; ++n) h[n] += xs[n][i] * wv;
    }
#pragma unroll
    for (int n = 0; n < ENV; ++n) hs[n][j] = fmaxf(h[n], 0.f);
    __syncthreads();
    float o[ENV];
#pragma unroll
    for (int n = 0; n < ENV; ++n) o[n] = eb2[j];
    for (int i = 0; i < 64; ++i) {
      float wv = ew2[i * 64 + j];
#pragma unroll
      for (int n = 0; n < ENV; ++n) o[n] += hs[n][i] * wv;
    }
#pragma unroll
    for (int n = 0; n < ENV; ++n) {
      o[n] = fmaxf(o[n], 0.f);
      enc[(bv0 + n) * 64 + j] = o[n];
    }
#pragma unroll
    for (int n = 0; n < ENV; ++n) {
#pragma unroll
      for (int hh = 0; hh < H; ++hh) {
        float v1 = wave_sum(o[n] * wa1[hh * 64 + j]);
        float v2 = wave_sum(o[n] * wa2[hh * 64 + j]);
        if (j == 0) {
          ss[(b * H + hh) * V + v0 + n] = v1;
          sn[(b * H + hh) * V + v0 + n] = v2;
        }
      }
    }
  } else if (blk < 3 * V) {
    int w = blk - 2 * V;
    w2t[w * 64 + j] = dec_w2[j * V + w];
  } else {
    int idx = (blk - 3 * V) * 64 + j;
    for (int i = idx; i < B * MAXNNZ; i += ZBLK * 64) fwe[i] = 0.f;
    for (int i = idx; i < MAXNNZ; i += ZBLK * 64) meta[i] = 0u;
  }
}

// ---- L2/L3: GAT layer. Aggregation loop restructured: 4-wide load batches so
// 4 eb-row gathers are in flight at once (was 1 serial ~200cyc chain per edge).
#define GNV 8
__global__ __launch_bounds__(256) void gat2_kernel(
    const float* __restrict__ enc_in, const float* __restrict__ ss_in,
    const float* __restrict__ sn_in, const int* __restrict__ nbr,
    const int* __restrict__ deg, const float* __restrict__ gat_w,
    const float* __restrict__ gate_w, const float* __restrict__ gate_u,
    const float* __restrict__ gate_b, const float* __restrict__ wa1,
    const float* __restrict__ wa2, float* __restrict__ enc_out,
    float* __restrict__ ss_out, float* __restrict__ sn_out, int write_s,
    const int* __restrict__ deg_in, int* __restrict__ slot_cur,
    int* __restrict__ csc_pos, int do_csc) {
  int b = blockIdx.x & 7;
  int v0 = (blockIdx.x >> 3) * GNV;
  int tid = threadIdx.x;  // 256
  int wid = tid >> 6, lane = tid & 63;
  __shared__ float agg[GNV][H][64];   // 8 KB
  __shared__ float gpart[GNV][4][64]; // 8 KB
  __shared__ float nxts[GNV][64];     // 2 KB
  __shared__ float encs[GNV][64];     // 2 KB
  __shared__ int ioff[V];             // 4 KB (csc tail)
  const float* eb = enc_in + (size_t)b * V * 64;
  for (int i = tid; i < GNV * 64; i += 256) encs[i >> 6][i & 63] = eb[v0 * 64 + i];
  for (int n = wid; n < GNV; n += 4) {
    int v = v0 + n;
    int dvv = deg[v];
    int wk = (lane < dvv) ? nbr[v * CAP + lane] : 0;
    float c[H];
#pragma unroll
    for (int h = 0; h < H; ++h) {
      float x = ss_in[(b * H + h) * V + v] + sn_in[(b * H + h) * V + wk];
      x = (x > 0.f) ? x : 0.2f * x;  // leaky_relu 0.2
      if (lane >= dvv) x = -1e30f;
      float m = wave_max(x);
      float e = (lane < dvv) ? __expf(x - m) : 0.f;
      float s = wave_sum(e);
      c[h] = e / s;
    }
    float a0 = 0.f, a1v = 0.f, a2v = 0.f, a3v = 0.f;
    for (int k0 = 0; k0 < dvv; k0 += 4) {
      int r = dvv - k0;  // wave-uniform
      int w0 = __shfl(wk, k0 & 63);
      int w1 = __shfl(wk, (k0 + 1) & 63);
      int w2 = __shfl(wk, (k0 + 2) & 63);
      int w3 = __shfl(wk, (k0 + 3) & 63);
      // issue up to 4 independent row loads before consuming any
      float e0 = eb[w0 * 64 + lane];
      float e1 = (r > 1) ? eb[w1 * 64 + lane] : 0.f;
      float e2 = (r > 2) ? eb[w2 * 64 + lane] : 0.f;
      float e3 = (r > 3) ? eb[w3 * 64 + lane] : 0.f;
      a0 += __shfl(c[0], k0 & 63) * e0;
      a1v += __shfl(c[1], k0 & 63) * e0;
      a2v += __shfl(c[2], k0 & 63) * e0;
      a3v += __shfl(c[3], k0 & 63) * e0;
      if (r > 1) {
        a0 += __shfl(c[0], (k0 + 1) & 63) * e1;
        a1v += __shfl(c[1], (k0 + 1) & 63) * e1;
        a2v += __shfl(c[2], (k0 + 1) & 63) * e1;
        a3v += __shfl(c[3], (k0 + 1) & 63) * e1;
      }
      if (r > 2) {
        a0 += __shfl(c[0], (k0 + 2) & 63) * e2;
        a1v += __shfl(c[1], (k0 + 2) & 63) * e2;
        a2v += __shfl(c[2], (k0 + 2) & 63) * e2;
        a3v += __shfl(c[3], (k0 + 2) & 63) * e2;
      }
      if (r > 3) {
        a0 += __shfl(c[0], (k0 + 3) & 63) * e3;
        a1v += __shfl(c[1], (k0 + 3) & 63) * e3;
        a2v += __shfl(c[2], (k0 + 3) & 63) * e3;
        a3v += __shfl(c[3], (k0 + 3) & 63) * e3;
      }
    }
    agg[n][0][lane] = a0;
    agg[n][1][lane] = a1v;
    agg[n][2][lane] = a2v;
    agg[n][3][lane] = a3v;
  }
  __syncthreads();
  {
    const float* W = gat_w + wid * 4096;
    float hv[GNV];
#pragma unroll
    for (int n = 0; n < GNV; ++n) hv[n] = 0.f;
    for (int f = 0; f < 64; ++f) {
      float wf = W[f * 64 + lane];
#pragma unroll
      for (int n = 0; n < GNV; ++n) hv[n] += agg[n][wid][f] * wf;
    }
#pragma unroll
    for (int n = 0; n < GNV; ++n) gpart[n][wid][lane] = hv[n];
  }
  __syncthreads();
  for (int i = tid; i < GNV * 64; i += 256) {
    int n = i >> 6, g = i & 63;
    float s4 = gpart[n][0][g] + gpart[n][1][g] + gpart[n][2][g] + gpart[n][3][g];
    nxts[n][g] = fmaxf(0.25f * s4, 0.f);
  }
  __syncthreads();
  {
    float part[GNV];
#pragma unroll
    for (int n = 0; n < GNV; ++n) part[n] = 0.f;
    for (int f = wid * 16; f < wid * 16 + 16; ++f) {
      float gw = gate_w[f * 64 + lane], gu = gate_u[f * 64 + lane];
#pragma unroll
      for (int n = 0; n < GNV; ++n) part[n] += nxts[n][f] * gw + encs[n][f] * gu;
    }
    __syncthreads();
#pragma unroll
    for (int n = 0; n < GNV; ++n) gpart[n][wid][lane] = part[n];
  }
  __syncthreads();
  for (int i = tid; i < GNV * 64; i += 256) {
    int n = i >> 6, g = i & 63;
    float zs = gpart[n][0][g] + gpart[n][1][g] + gpart[n][2][g] + gpart[n][3][g] + gate_b[g];
    float z = 1.f / (1.f + __expf(-zs));
    float out = z * nxts[n][g] + (1.f - z) * encs[n][g];
    encs[n][g] = out;  // reuse as output buffer
    enc_out[((size_t)b * V + v0 + n) * 64 + g] = out;
  }
  if (write_s) {
    __syncthreads();
    float w1v = wa1[wid * 64 + lane], w2v = wa2[wid * 64 + lane];
#pragma unroll
    for (int n = 0; n < GNV; ++n) {
      float e = encs[n][lane];
      float ssv = wave_sum(e * w1v);
      float snv = wave_sum(e * w2v);
      if (lane == 0) {
        ss_out[(b * H + wid) * V + v0 + n] = ssv;
        sn_out[(b * H + wid) * V + v0 + n] = snv;
      }
    }
  }
  if (do_csc && b == 0) {  // exactly once per v-group
    __syncthreads();
    if (tid < 64) {
      int vals[16];
      int tot = 0;
#pragma unroll
      for (int i = 0; i < 16; ++i) {
        vals[i] = tot;
        tot += deg_in[tid * 16 + i];
      }
      int run = tot;
      for (int o = 1; o < 64; o <<= 1) {
        int u = __shfl_up(run, o);
        if (lane >= o) run += u;
      }
      int excl = run - tot;
#pragma unroll
      for (int i = 0; i < 16; ++i) ioff[tid * 16 + i] = excl + vals[i];
    }
    __syncthreads();
    for (int n = wid; n < GNV; n += 4) {
      int v = v0 + n;
      if (lane < deg[v]) {
        int w = nbr[v * CAP + lane];
        csc_pos[v * CAP + lane] = ioff[w] + atomicAdd(&slot_cur[w], 1);
      }
    }
  }
}

// ---- L4: fused decoder+dual+flow-weights (4 nodes/block, lane-per-edge fw) ----
#define DNV 4
__global__ __launch_bounds__(256) void decfw_kernel(
    const float* __restrict__ enc, const float* __restrict__ dw1,
    const float* __restrict__ db1, const float* __restrict__ uw1,
    const float* __restrict__ ub1, const float* __restrict__ uw2,
    const float* __restrict__ ub2, const float* __restrict__ w2t,
    const float* __restrict__ dec_b2, const int* __restrict__ nbr,
    const int* __restrict__ deg, const int* __restrict__ csc_pos,
    float* __restrict__ fwe, unsigned int* __restrict__ meta,
    float* __restrict__ rssq, float* __restrict__ dvout) {
  int b = blockIdx.x & 7;
  int v0 = (blockIdx.x >> 3) * DNV;
  int bv0 = b * V + v0;
  int tid = threadIdx.x;  // 256
  int wv = tid >> 6, j = tid & 63;
  __shared__ float es[DNV][64];
  __shared__ float hs[DNV][64];
  es[wv][j] = enc[(bv0 + wv) * 64 + j];
  __syncthreads();
  float hj = db1[j], uj = ub1[j];
  for (int f = 0; f < 64; ++f) {
    hj += es[wv][f] * dw1[f * 64 + j];
    uj += es[wv][f] * uw1[f * 64 + j];
  }
  hs[wv][j] = hj;  // NO relu: decoder is linear
  float sdv = wave_sum(uj * uw2[j]);
  if (j == 0) dvout[bv0 + wv] = sdv + ub2[0];
  __syncthreads();
  int v = v0 + wv;
  int dvv = deg[v];
  int w = (j < dvv) ? nbr[v * CAP + j] : 0;
  const float4* wrow = (const float4*)(w2t + w * 64);
  const float4* hv4 = (const float4*)hs[wv];
  float d = 0.f;
#pragma unroll
  for (int f = 0; f < 16; ++f) {
    float4 wvv = wrow[f];
    float4 hv = hv4[f];  // LDS broadcast
    d += hv.x * wvv.x + hv.y * wvv.y + hv.z * wvv.z + hv.w * wvv.w;
  }
  d += dec_b2[w];
  float pp = d * d;
  float myp = (j < dvv) ? pp : -1e30f;
  float m = wave_max(myp);
  float e = (j < dvv) ? __expf(myp - m) : 0.f;
  float s = wave_sum(e);
  float coef = e / s;
  if (j < dvv) {
    int idx = csc_pos[v * CAP + j];
    fwe[(size_t)b * MAXNNZ + idx] = coef;
    meta[idx] = (unsigned)v | ((unsigned)w << 16);
  }
  float r = wave_sum(coef * coef);
  if (j == 0) rssq[bv0 + wv] = r;
}

// ---- L5: flow iterations + dual (int4-vectorized gather) + final ----
__global__ __launch_bounds__(1024) void flow_dual_kernel(
    const float* __restrict__ fwe, const unsigned* __restrict__ meta,
    const float* __restrict__ rssq, const float* __restrict__ dv,
    const float* __restrict__ demands, const int* __restrict__ nbr_out,
    const int* __restrict__ deg_out, float* __restrict__ partial,
    unsigned* __restrict__ done, float* __restrict__ out) {
  int b = blockIdx.x;
  int v = threadIdx.x;  // 1024
  __shared__ float o[V], infl[V], dvs[V];
  __shared__ float red[16];
  float dem = demands[b * V + v];
  dvs[v] = dv[b * V + v];
  o[v] = fmaxf(-dem, 0.f);  // o_1 = relu(-demand)
  infl[v] = 0.f;
  const float4* fp = (const float4*)(fwe + (size_t)b * MAXNNZ + v * SE);
  const uint4* mp = (const uint4*)(meta + v * SE);
  float fr[SE];
  unsigned mr[SE];
#pragma unroll
  for (int i = 0; i < SE / 4; ++i) {
    float4 f4 = fp[i];
    uint4 m4 = mp[i];
    fr[4 * i + 0] = f4.x; fr[4 * i + 1] = f4.y; fr[4 * i + 2] = f4.z; fr[4 * i + 3] = f4.w;
    mr[4 * i + 0] = m4.x; mr[4 * i + 1] = m4.y; mr[4 * i + 2] = m4.z; mr[4 * i + 3] = m4.w;
  }
  __syncthreads();
  for (int it = 0; it < 9; ++it) {
    float acc = 0.f;
    int pdst = -1;
#pragma unroll
    for (int i = 0; i < SE; ++i) {
      int src = mr[i] & 0xFFFF;
      int dst = mr[i] >> 16;
      if (dst != pdst) {
        if (acc != 0.f) atomicAdd(&infl[pdst], acc);
        acc = 0.f;
        pdst = dst;
      }
      acc += fr[i] * o[src];
    }
    if (acc != 0.f) atomicAdd(&infl[pdst], acc);
    __syncthreads();
    float nv = fmaxf(infl[v] - dem, 0.f);
    o[v] = nv;
    infl[v] = 0.f;
    __syncthreads();
  }
  float o10 = o[v];
  float local = o10 * o10 * rssq[b * V + v];
  // dual: vectorized nbr row reads (int4) + guarded 4-wide consumption
  float dvv = dvs[v];
  int dout = deg_out[v];
  float acc = 0.f;
  for (int k0 = 0; k0 < dout; k0 += 4) {
    int4 nn = *(const int4*)(nbr_out + v * CAP + k0);
    int r = dout - k0;
    float d0 = dvv - dvs[nn.x];
    if (d0 > 0.f) acc += d0 * d0;
    if (r > 1) { float d1 = dvv - dvs[nn.y]; if (d1 > 0.f) acc += d1 * d1; }
    if (r > 2) { float d2 = dvv - dvs[nn.z]; if (d2 > 0.f) acc += d2 * d2; }
    if (r > 3) { float d3 = dvv - dvs[nn.w]; if (d3 > 0.f) acc += d3 * d3; }
  }
  local += 0.25f * acc + dvv * dem;
  local = wave_sum(local);
  if ((v & 63) == 0) red[v >> 6] = local;
  __syncthreads();
  if (v < 16) {
    float r = red[v];
    for (int o2 = 8; o2 > 0; o2 >>= 1) r += __shfl_xor(r, o2, 16);
    if (v == 0) {
      __hip_atomic_store(&partial[b], r, __ATOMIC_RELEASE, __HIP_MEMORY_SCOPE_AGENT);
      unsigned old = __hip_atomic_fetch_add(done, 1u, __ATOMIC_ACQ_REL, __HIP_MEMORY_SCOPE_AGENT);
      if (old == B - 1) {  // last block: deterministic fixed-order sum
        float s = 0.f;
        for (int i = 0; i < B; ++i)
          s += __hip_atomic_load(&partial[i], __ATOMIC_ACQUIRE, __HIP_MEMORY_SCOPE_AGENT);
        out[0] = s * (1.0f / B);
      }
    }
  }
}

extern "C" void kernel_launch(void* const* d_in, const int* in_sizes, int n_in,
                              void* d_out, int out_size, void* d_ws, size_t ws_size,
                              hipStream_t stream) {
  const float* demands = (const float*)d_in[0];
  const float* emb     = (const float*)d_in[1];
  const float* adj     = (const float*)d_in[2];
  const float* enc_w1  = (const float*)d_in[3];
  const float* enc_b1  = (const float*)d_in[4];
  const float* enc_w2  = (const float*)d_in[5];
  const float* enc_b2  = (const float*)d_in[6];
  const float* gat_w   = (const float*)d_in[7];
  const float* gat_a1  = (const float*)d_in[8];
  const float* gat_a2  = (const float*)d_in[9];
  const float* gate_w  = (const float*)d_in[10];
  const float* gate_u  = (const float*)d_in[11];
  const float* gate_b  = (const float*)d_in[12];
  const float* dec_w1  = (const float*)d_in[13];
  const float* dec_b1  = (const float*)d_in[14];
  const float* dec_w2  = (const float*)d_in[15];
  const float* dec_b2  = (const float*)d_in[16];
  const float* dual_w1 = (const float*)d_in[17];
  const float* dual_b1 = (const float*)d_in[18];
  const float* dual_w2 = (const float*)d_in[19];
  const float* dual_b2 = (const float*)d_in[20];

  char* pz = (char*)d_ws;
  int* deg_in   = (int*)pz;                 // 4096 B (zeroed by zero_wa)
  int* slot_cur = (int*)(pz + 4096);        // 4096 B (zeroed by zero_wa)
  unsigned* done = (unsigned*)(pz + 8192);  // 4 B    (zeroed by zero_wa)
  char* p = pz + 8448;
  auto alloc = [&](size_t n) { void* r = (void*)p; p += (n + 255) & ~(size_t)255; return r; };
  int* nbr_out   = (int*)alloc((size_t)V * CAP * 4);
  int* deg_out   = (int*)alloc((size_t)V * 4);
  int* csc_pos   = (int*)alloc((size_t)V * CAP * 4);
  float* fwe     = (float*)alloc((size_t)B * MAXNNZ * 4);
  unsigned int* meta = (unsigned int*)alloc((size_t)MAXNNZ * 4);
  float* w2t     = (float*)alloc((size_t)64 * V * 4);
  float* wa1     = (float*)alloc((size_t)H * 64 * 4);
  float* wa2     = (float*)alloc((size_t)H * 64 * 4);
  float* encA    = (float*)alloc((size_t)B * V * 64 * 4);
  float* encB    = (float*)alloc((size_t)B * V * 64 * 4);
  float* ssA     = (float*)alloc((size_t)B * H * V * 4);
  float* snA     = (float*)alloc((size_t)B * H * V * 4);
  float* ssB     = (float*)alloc((size_t)B * H * V * 4);
  float* snB     = (float*)alloc((size_t)B * H * V * 4);
  float* dv      = (float*)alloc((size_t)B * V * 4);
  float* rssq    = (float*)alloc((size_t)B * V * 4);
  float* partial = (float*)alloc((size_t)B * 4);

  zero_wa_kernel<<<9, 256, 0, stream>>>(deg_in, slot_cur, done, gat_w, gat_a1, gat_a2,
                                        wa1, wa2);
  setup_kernel<<<3 * V + ZBLK, 64, 0, stream>>>(
      adj, demands, emb, enc_w1, enc_b1, enc_w2, enc_b2, dec_w2, wa1, wa2,
      nbr_out, deg_out, deg_in, encA, ssA, snA, w2t, fwe, meta);
  gat2_kernel<<<B * V / GNV, 256, 0, stream>>>(encA, ssA, snA, nbr_out, deg_out, gat_w,
                                               gate_w, gate_u, gate_b, wa1, wa2,
                                               encB, ssB, snB, 1,
                                               deg_in, slot_cur, csc_pos, 1);
  gat2_kernel<<<B * V / GNV, 256, 0, stream>>>(encB, ssB, snB, nbr_out, deg_out, gat_w,
                                               gate_w, gate_u, gate_b, wa1, wa2,
                                               encA, ssA, snA, 0,
                                               deg_in, slot_cur, csc_pos, 0);
  decfw_kernel<<<B * V / DNV, 256, 0, stream>>>(encA, dec_w1, dec_b1, dual_w1, dual_b1,
                                                dual_w2, dual_b2, w2t, dec_b2, nbr_out,
                                                deg_out, csc_pos, fwe, meta, rssq, dv);
  flow_dual_kernel<<<B, 1024, 0, stream>>>(fwe, meta, rssq, dv, demands, nbr_out, deg_out,
                                           partial, done, (float*)d_out);
}

// Round 16
// 148.577 us; speedup vs baseline: 1.0031x; 1.0031x over previous
//
#include <hip/hip_runtime.h>
#include <math.h>

#define B 8
#define V 1024
#define E 32
#define H 4
#define CAP 64        // max out-degree capacity; E[deg]=17, P(deg>64) ~ 1e-21
#define MAXNNZ 20480  // nnz ~ 17390 +/- 128; +24 sigma headroom
#define SE (MAXNNZ / V)  // 20 edges per thread in flow kernel
#define ZBLK 128      // zero-role blocks in setup kernel

// XCD-aware decode: blockIdx round-robins across 8 XCDs on MI355X, and B==8.
// b = blockIdx & 7 pins each batch to one XCD -> per-XCD working set fits 4MB L2.

__device__ __forceinline__ float wave_sum(float v) {
  for (int o = 32; o > 0; o >>= 1) v += __shfl_xor(v, o);
  return v;
}
__device__ __forceinline__ float wave_max(float v) {
  for (int o = 32; o > 0; o >>= 1) v = fmaxf(v, __shfl_xor(v, o));
  return v;
}

// ---- L0: zero deg_in/slot_cur/done + precompute wa1/wa2 = gat_w @ a1/a2 ----
__global__ void zero_wa_kernel(int* __restrict__ deg_in, int* __restrict__ slot_cur,
                               unsigned* __restrict__ done, const float* __restrict__ gat_w,
                               const float* __restrict__ a1, const float* __restrict__ a2,
                               float* __restrict__ wa1, float* __restrict__ wa2) {
  int blk = blockIdx.x, tid = threadIdx.x;
  if (blk < 4) {
    deg_in[blk * 256 + tid] = 0;
  } else if (blk < 8) {
    slot_cur[(blk - 4) * 256 + tid] = 0;
  } else {
    if (tid == 0) *done = 0u;
    int h = tid >> 6, f = tid & 63;
    float s1 = 0.f, s2 = 0.f;
    const float* W = gat_w + h * 4096 + f * 64;
    for (int g = 0; g < 64; ++g) {
      float w = W[g];
      s1 += w * a1[h * 64 + g];
      s2 += w * a2[h * 64 + g];
    }
    wa1[h * 64 + f] = s1;
    wa2[h * 64 + f] = s2;
  }
}

// ---- L1: merged setup (64-thread blocks, role by blockIdx) ----
#define ENV 8
__global__ void setup_kernel(const float* __restrict__ adj, const float* __restrict__ demands,
                             const float* __restrict__ emb,
                             const float* __restrict__ ew1, const float* __restrict__ eb1,
                             const float* __restrict__ ew2, const float* __restrict__ eb2,
                             const float* __restrict__ dec_w2,
                             const float* __restrict__ wa1, const float* __restrict__ wa2,
                             int* __restrict__ nbr, int* __restrict__ deg,
                             int* __restrict__ deg_in, float* __restrict__ enc,
                             float* __restrict__ ss, float* __restrict__ sn,
                             float* __restrict__ w2t, float* __restrict__ fwe,
                             unsigned int* __restrict__ meta) {
  int blk = blockIdx.x;
  int j = threadIdx.x;  // 64
  if (blk < V) {
    int v = blk;
    int base = 0;
    for (int c = 0; c < V; c += 64) {
      float a = adj[v * V + c + j];
      unsigned long long m = __ballot(a > 0.5f);
      int pos = __popcll(m & ((1ull << j) - 1ull));
      if (a > 0.5f && base + pos < CAP) {
        nbr[v * CAP + base + pos] = c + j;
        atomicAdd(&deg_in[c + j], 1);
      }
      base += __popcll(m);
    }
    if (j == 0) deg[v] = (base < CAP) ? base : CAP;
  } else if (blk < 2 * V) {
    int eb = blk - V;
    int b = eb & 7;
    int v0 = (eb >> 3) * ENV;
    int bv0 = b * V + v0;
    __shared__ float xs[ENV][E + 1];
    __shared__ float hs[ENV][64];
#pragma unroll
    for (int n = 0; n < ENV; ++n) {
      if (j < E) xs[n][j] = emb[(v0 + n) * E + j];
      else if (j == E) xs[n][E] = demands[b * V + v0 + n];
    }
    __syncthreads();
    float h[ENV];
#pragma unroll
    for (int n = 0; n < ENV; ++n) h[n] = eb1[j];
    for (int i = 0; i < E + 1; ++i) {
      float wv = ew1[i * 64 + j];
#pragma unroll
      for (int n = 0; n < ENV; ++n) h[n] += xs[n][i] * wv;
    }
#pragma unroll
    for (int n = 0; n < ENV; ++n) hs[n][j] = fmaxf(h[n], 0.f);
    __syncthreads();
    float o[ENV];
#pragma unroll
    for (int n = 0; n < ENV; ++n) o[n] = eb2[j];
    for (int i = 0; i < 64; ++i) {
      float wv = ew2[i * 64 + j];
#pragma unroll
      for (int n = 0; n < ENV; ++n) o[n] += hs[n][i] * wv;
    }
#pragma unroll
    for (int n = 0; n < ENV; ++n) {
      o[n] = fmaxf(o[n], 0.f);
      enc[(bv0 + n) * 64 + j] = o[n];
    }
#pragma unroll
    for (int n = 0; n < ENV; ++n) {
#pragma unroll
      for (int hh = 0; hh < H; ++hh) {
        float v1 = wave_sum(o[n] * wa1[hh * 64 + j]);
        float v2 = wave_sum(o[n] * wa2[hh * 64 + j]);
        if (j == 0) {
          ss[(b * H + hh) * V + v0 + n] = v1;
          sn[(b * H + hh) * V + v0 + n] = v2;
        }
      }
    }
  } else if (blk < 3 * V) {
    int w = blk - 2 * V;
    w2t[w * 64 + j] = dec_w2[j * V + w];
  } else {
    int idx = (blk - 3 * V) * 64 + j;
    for (int i = idx; i < B * MAXNNZ; i += ZBLK * 64) fwe[i] = 0.f;
    for (int i = idx; i < MAXNNZ; i += ZBLK * 64) meta[i] = 0u;
  }
}

// ---- L2/L3: GAT layer (aggregate-then-project, 4-wide load batches) ----
#define GNV 8
__global__ __launch_bounds__(256) void gat2_kernel(
    const float* __restrict__ enc_in, const float* __restrict__ ss_in,
    const float* __restrict__ sn_in, const int* __restrict__ nbr,
    const int* __restrict__ deg, const float* __restrict__ gat_w,
    const float* __restrict__ gate_w, const float* __restrict__ gate_u,
    const float* __restrict__ gate_b, const float* __restrict__ wa1,
    const float* __restrict__ wa2, float* __restrict__ enc_out,
    float* __restrict__ ss_out, float* __restrict__ sn_out, int write_s,
    const int* __restrict__ deg_in, int* __restrict__ slot_cur,
    int* __restrict__ csc_pos, int do_csc) {
  int b = blockIdx.x & 7;
  int v0 = (blockIdx.x >> 3) * GNV;
  int tid = threadIdx.x;  // 256
  int wid = tid >> 6, lane = tid & 63;
  __shared__ float agg[GNV][H][64];   // 8 KB
  __shared__ float gpart[GNV][4][64]; // 8 KB
  __shared__ float nxts[GNV][64];     // 2 KB
  __shared__ float encs[GNV][64];     // 2 KB
  __shared__ int ioff[V];             // 4 KB (csc tail)
  const float* eb = enc_in + (size_t)b * V * 64;
  for (int i = tid; i < GNV * 64; i += 256) encs[i >> 6][i & 63] = eb[v0 * 64 + i];
  for (int n = wid; n < GNV; n += 4) {
    int v = v0 + n;
    int dvv = deg[v];
    int wk = (lane < dvv) ? nbr[v * CAP + lane] : 0;
    float c[H];
#pragma unroll
    for (int h = 0; h < H; ++h) {
      float x = ss_in[(b * H + h) * V + v] + sn_in[(b * H + h) * V + wk];
      x = (x > 0.f) ? x : 0.2f * x;  // leaky_relu 0.2
      if (lane >= dvv) x = -1e30f;
      float m = wave_max(x);
      float e = (lane < dvv) ? __expf(x - m) : 0.f;
      float s = wave_sum(e);
      c[h] = e / s;
    }
    float a0 = 0.f, a1v = 0.f, a2v = 0.f, a3v = 0.f;
    for (int k0 = 0; k0 < dvv; k0 += 4) {
      int r = dvv - k0;  // wave-uniform
      int w0 = __shfl(wk, k0 & 63);
      int w1 = __shfl(wk, (k0 + 1) & 63);
      int w2 = __shfl(wk, (k0 + 2) & 63);
      int w3 = __shfl(wk, (k0 + 3) & 63);
      float e0 = eb[w0 * 64 + lane];
      float e1 = (r > 1) ? eb[w1 * 64 + lane] : 0.f;
      float e2 = (r > 2) ? eb[w2 * 64 + lane] : 0.f;
      float e3 = (r > 3) ? eb[w3 * 64 + lane] : 0.f;
      a0 += __shfl(c[0], k0 & 63) * e0;
      a1v += __shfl(c[1], k0 & 63) * e0;
      a2v += __shfl(c[2], k0 & 63) * e0;
      a3v += __shfl(c[3], k0 & 63) * e0;
      if (r > 1) {
        a0 += __shfl(c[0], (k0 + 1) & 63) * e1;
        a1v += __shfl(c[1], (k0 + 1) & 63) * e1;
        a2v += __shfl(c[2], (k0 + 1) & 63) * e1;
        a3v += __shfl(c[3], (k0 + 1) & 63) * e1;
      }
      if (r > 2) {
        a0 += __shfl(c[0], (k0 + 2) & 63) * e2;
        a1v += __shfl(c[1], (k0 + 2) & 63) * e2;
        a2v += __shfl(c[2], (k0 + 2) & 63) * e2;
        a3v += __shfl(c[3], (k0 + 2) & 63) * e2;
      }
      if (r > 3) {
        a0 += __shfl(c[0], (k0 + 3) & 63) * e3;
        a1v += __shfl(c[1], (k0 + 3) & 63) * e3;
        a2v += __shfl(c[2], (k0 + 3) & 63) * e3;
        a3v += __shfl(c[3], (k0 + 3) & 63) * e3;
      }
    }
    agg[n][0][lane] = a0;
    agg[n][1][lane] = a1v;
    agg[n][2][lane] = a2v;
    agg[n][3][lane] = a3v;
  }
  __syncthreads();
  {
    const float* W = gat_w + wid * 4096;
    float hv[GNV];
#pragma unroll
    for (int n = 0; n < GNV; ++n) hv[n] = 0.f;
    for (int f = 0; f < 64; ++f) {
      float wf = W[f * 64 + lane];
#pragma unroll
      for (int n = 0; n < GNV; ++n) hv[n] += agg[n][wid][f] * wf;
    }
#pragma unroll
    for (int n = 0; n < GNV; ++n) gpart[n][wid][lane] = hv[n];
  }
  __syncthreads();
  for (int i = tid; i < GNV * 64; i += 256) {
    int n = i >> 6, g = i & 63;
    float s4 = gpart[n][0][g] + gpart[n][1][g] + gpart[n][2][g] + gpart[n][3][g];
    nxts[n][g] = fmaxf(0.25f * s4, 0.f);
  }
  __syncthreads();
  {
    float part[GNV];
#pragma unroll
    for (int n = 0; n < GNV; ++n) part[n] = 0.f;
    for (int f = wid * 16; f < wid * 16 + 16; ++f) {
      float gw = gate_w[f * 64 + lane], gu = gate_u[f * 64 + lane];
#pragma unroll
      for (int n = 0; n < GNV; ++n) part[n] += nxts[n][f] * gw + encs[n][f] * gu;
    }
    __syncthreads();
#pragma unroll
    for (int n = 0; n < GNV; ++n) gpart[n][wid][lane] = part[n];
  }
  __syncthreads();
  for (int i = tid; i < GNV * 64; i += 256) {
    int n = i >> 6, g = i & 63;
    float zs = gpart[n][0][g] + gpart[n][1][g] + gpart[n][2][g] + gpart[n][3][g] + gate_b[g];
    float z = 1.f / (1.f + __expf(-zs));
    float out = z * nxts[n][g] + (1.f - z) * encs[n][g];
    encs[n][g] = out;  // reuse as output buffer
    enc_out[((size_t)b * V + v0 + n) * 64 + g] = out;
  }
  if (write_s) {
    __syncthreads();
    float w1v = wa1[wid * 64 + lane], w2v = wa2[wid * 64 + lane];
#pragma unroll
    for (int n = 0; n < GNV; ++n) {
      float e = encs[n][lane];
      float ssv = wave_sum(e * w1v);
      float snv = wave_sum(e * w2v);
      if (lane == 0) {
        ss_out[(b * H + wid) * V + v0 + n] = ssv;
        sn_out[(b * H + wid) * V + v0 + n] = snv;
      }
    }
  }
  if (do_csc && b == 0) {  // exactly once per v-group
    __syncthreads();
    if (tid < 64) {
      int vals[16];
      int tot = 0;
#pragma unroll
      for (int i = 0; i < 16; ++i) {
        vals[i] = tot;
        tot += deg_in[tid * 16 + i];
      }
      int run = tot;
      for (int o = 1; o < 64; o <<= 1) {
        int u = __shfl_up(run, o);
        if (lane >= o) run += u;
      }
      int excl = run - tot;
#pragma unroll
      for (int i = 0; i < 16; ++i) ioff[tid * 16 + i] = excl + vals[i];
    }
    __syncthreads();
    for (int n = wid; n < GNV; n += 4) {
      int v = v0 + n;
      if (lane < deg[v]) {
        int w = nbr[v * CAP + lane];
        csc_pos[v * CAP + lane] = ioff[w] + atomicAdd(&slot_cur[w], 1);
      }
    }
  }
}

// ---- L4: fused decoder+dual+flow-weights (4 nodes/block, lane-per-edge fw) ----
#define DNV 4
__global__ __launch_bounds__(256) void decfw_kernel(
    const float* __restrict__ enc, const float* __restrict__ dw1,
    const float* __restrict__ db1, const float* __restrict__ uw1,
    const float* __restrict__ ub1, const float* __restrict__ uw2,
    const float* __restrict__ ub2, const float* __restrict__ w2t,
    const float* __restrict__ dec_b2, const int* __restrict__ nbr,
    const int* __restrict__ deg, const int* __restrict__ csc_pos,
    float* __restrict__ fwe, unsigned int* __restrict__ meta,
    float* __restrict__ rssq, float* __restrict__ dvout) {
  int b = blockIdx.x & 7;
  int v0 = (blockIdx.x >> 3) * DNV;
  int bv0 = b * V + v0;
  int tid = threadIdx.x;  // 256
  int wv = tid >> 6, j = tid & 63;
  __shared__ float es[DNV][64];
  __shared__ float hs[DNV][64];
  es[wv][j] = enc[(bv0 + wv) * 64 + j];
  __syncthreads();
  float hj = db1[j], uj = ub1[j];
  for (int f = 0; f < 64; ++f) {
    hj += es[wv][f] * dw1[f * 64 + j];
    uj += es[wv][f] * uw1[f * 64 + j];
  }
  hs[wv][j] = hj;  // NO relu: decoder is linear
  float sdv = wave_sum(uj * uw2[j]);
  if (j == 0) dvout[bv0 + wv] = sdv + ub2[0];
  __syncthreads();
  int v = v0 + wv;
  int dvv = deg[v];
  int w = (j < dvv) ? nbr[v * CAP + j] : 0;
  const float4* wrow = (const float4*)(w2t + w * 64);
  const float4* hv4 = (const float4*)hs[wv];
  float d = 0.f;
#pragma unroll
  for (int f = 0; f < 16; ++f) {
    float4 wvv = wrow[f];
    float4 hv = hv4[f];  // LDS broadcast
    d += hv.x * wvv.x + hv.y * wvv.y + hv.z * wvv.z + hv.w * wvv.w;
  }
  d += dec_b2[w];
  float pp = d * d;
  float myp = (j < dvv) ? pp : -1e30f;
  float m = wave_max(myp);
  float e = (j < dvv) ? __expf(myp - m) : 0.f;
  float s = wave_sum(e);
  float coef = e / s;
  if (j < dvv) {
    int idx = csc_pos[v * CAP + j];
    fwe[(size_t)b * MAXNNZ + idx] = coef;
    meta[idx] = (unsigned)v | ((unsigned)w << 16);
  }
  float r = wave_sum(coef * coef);
  if (j == 0) rssq[bv0 + wv] = r;
}

// ---- L5: flow iterations (batched LDS loads -> registers, then branchy
//      accumulation on registers only) + scalar dual + folded final ----
__global__ __launch_bounds__(1024) void flow_dual_kernel(
    const float* __restrict__ fwe, const unsigned* __restrict__ meta,
    const float* __restrict__ rssq, const float* __restrict__ dv,
    const float* __restrict__ demands, const int* __restrict__ nbr_out,
    const int* __restrict__ deg_out, float* __restrict__ partial,
    unsigned* __restrict__ done, float* __restrict__ out) {
  int b = blockIdx.x;
  int v = threadIdx.x;  // 1024
  __shared__ float o[V], infl[V], dvs[V];
  __shared__ float red[16];
  float dem = demands[b * V + v];
  dvs[v] = dv[b * V + v];
  o[v] = fmaxf(-dem, 0.f);  // o_1 = relu(-demand)
  infl[v] = 0.f;
  const float4* fp = (const float4*)(fwe + (size_t)b * MAXNNZ + v * SE);
  const uint4* mp = (const uint4*)(meta + v * SE);
  float fr[SE];
  unsigned mr[SE];
#pragma unroll
  for (int i = 0; i < SE / 4; ++i) {
    float4 f4 = fp[i];
    uint4 m4 = mp[i];
    fr[4 * i + 0] = f4.x; fr[4 * i + 1] = f4.y; fr[4 * i + 2] = f4.z; fr[4 * i + 3] = f4.w;
    mr[4 * i + 0] = m4.x; mr[4 * i + 1] = m4.y; mr[4 * i + 2] = m4.z; mr[4 * i + 3] = m4.w;
  }
  __syncthreads();
  for (int it = 0; it < 9; ++it) {
    // phase 1: issue ALL 20 gathers back-to-back (no branches between loads;
    // one waitcnt covers the batch instead of 20 serial latency exposures)
    float ov[SE];
#pragma unroll
    for (int i = 0; i < SE; ++i) ov[i] = o[mr[i] & 0xFFFF];
    // phase 2: branchy run-accumulation entirely on registers
    float acc = 0.f;
    int pdst = -1;
#pragma unroll
    for (int i = 0; i < SE; ++i) {
      int dst = mr[i] >> 16;
      if (dst != pdst) {
        if (acc != 0.f) atomicAdd(&infl[pdst], acc);
        acc = 0.f;
        pdst = dst;
      }
      acc += fr[i] * ov[i];
    }
    if (acc != 0.f) atomicAdd(&infl[pdst], acc);
    __syncthreads();
    float nv = fmaxf(infl[v] - dem, 0.f);
    o[v] = nv;
    infl[v] = 0.f;
    __syncthreads();
  }
  float o10 = o[v];
  float local = o10 * o10 * rssq[b * V + v];
  // dual: scalar loop (R14 form; R15's int4 variant measured -3.5us)
  float dvv = dvs[v];
  int dout = deg_out[v];
  float acc = 0.f;
  for (int k = 0; k < dout; ++k) {
    float diff = dvv - dvs[nbr_out[v * CAP + k]];
    if (diff > 0.f) acc += diff * diff;
  }
  local += 0.25f * acc + dvv * dem;
  local = wave_sum(local);
  if ((v & 63) == 0) red[v >> 6] = local;
  __syncthreads();
  if (v < 16) {
    float r = red[v];
    for (int o2 = 8; o2 > 0; o2 >>= 1) r += __shfl_xor(r, o2, 16);
    if (v == 0) {
      __hip_atomic_store(&partial[b], r, __ATOMIC_RELEASE, __HIP_MEMORY_SCOPE_AGENT);
      unsigned old = __hip_atomic_fetch_add(done, 1u, __ATOMIC_ACQ_REL, __HIP_MEMORY_SCOPE_AGENT);
      if (old == B - 1) {  // last block: deterministic fixed-order sum
        float s = 0.f;
        for (int i = 0; i < B; ++i)
          s += __hip_atomic_load(&partial[i], __ATOMIC_ACQUIRE, __HIP_MEMORY_SCOPE_AGENT);
        out[0] = s * (1.0f / B);
      }
    }
  }
}

extern "C" void kernel_launch(void* const* d_in, const int* in_sizes, int n_in,
                              void* d_out, int out_size, void* d_ws, size_t ws_size,
                              hipStream_t stream) {
  const float* demands = (const float*)d_in[0];
  const float* emb     = (const float*)d_in[1];
  const float* adj     = (const float*)d_in[2];
  const float* enc_w1  = (const float*)d_in[3];
  const float* enc_b1  = (const float*)d_in[4];
  const float* enc_w2  = (const float*)d_in[5];
  const float* enc_b2  = (const float*)d_in[6];
  const float* gat_w   = (const float*)d_in[7];
  const float* gat_a1  = (const float*)d_in[8];
  const float* gat_a2  = (const float*)d_in[9];
  const float* gate_w  = (const float*)d_in[10];
  const float* gate_u  = (const float*)d_in[11];
  const float* gate_b  = (const float*)d_in[12];
  const float* dec_w1  = (const float*)d_in[13];
  const float* dec_b1  = (const float*)d_in[14];
  const float* dec_w2  = (const float*)d_in[15];
  const float* dec_b2  = (const float*)d_in[16];
  const float* dual_w1 = (const float*)d_in[17];
  const float* dual_b1 = (const float*)d_in[18];
  const float* dual_w2 = (const float*)d_in[19];
  const float* dual_b2 = (const float*)d_in[20];

  char* pz = (char*)d_ws;
  int* deg_in   = (int*)pz;                 // 4096 B (zeroed by zero_wa)
  int* slot_cur = (int*)(pz + 4096);        // 4096 B (zeroed by zero_wa)
  unsigned* done = (unsigned*)(pz + 8192);  // 4 B    (zeroed by zero_wa)
  char* p = pz + 8448;
  auto alloc = [&](size_t n) { void* r = (void*)p; p += (n + 255) & ~(size_t)255; return r; };
  int* nbr_out   = (int*)alloc((size_t)V * CAP * 4);
  int* deg_out   = (int*)alloc((size_t)V * 4);
  int* csc_pos   = (int*)alloc((size_t)V * CAP * 4);
  float* fwe     = (float*)alloc((size_t)B * MAXNNZ * 4);
  unsigned int* meta = (unsigned int*)alloc((size_t)MAXNNZ * 4);
  float* w2t     = (float*)alloc((size_t)64 * V * 4);
  float* wa1     = (float*)alloc((size_t)H * 64 * 4);
  float* wa2     = (float*)alloc((size_t)H * 64 * 4);
  float* encA    = (float*)alloc((size_t)B * V * 64 * 4);
  float* encB    = (float*)alloc((size_t)B * V * 64 * 4);
  float* ssA     = (float*)alloc((size_t)B * H * V * 4);
  float* snA     = (float*)alloc((size_t)B * H * V * 4);
  float* ssB     = (float*)alloc((size_t)B * H * V * 4);
  float* snB     = (float*)alloc((size_t)B * H * V * 4);
  float* dv      = (float*)alloc((size_t)B * V * 4);
  float* rssq    = (float*)alloc((size_t)B * V * 4);
  float* partial = (float*)alloc((size_t)B * 4);

  zero_wa_kernel<<<9, 256, 0, stream>>>(deg_in, slot_cur, done, gat_w, gat_a1, gat_a2,
                                        wa1, wa2);
  setup_kernel<<<3 * V + ZBLK, 64, 0, stream>>>(
      adj, demands, emb, enc_w1, enc_b1, enc_w2, enc_b2, dec_w2, wa1, wa2,
      nbr_out, deg_out, deg_in, encA, ssA, snA, w2t, fwe, meta);
  gat2_kernel<<<B * V / GNV, 256, 0, stream>>>(encA, ssA, snA, nbr_out, deg_out, gat_w,
                                               gate_w, gate_u, gate_b, wa1, wa2,
                                               encB, ssB, snB, 1,
                                               deg_in, slot_cur, csc_pos, 1);
  gat2_kernel<<<B * V / GNV, 256, 0, stream>>>(encB, ssB, snB, nbr_out, deg_out, gat_w,
                                               gate_w, gate_u, gate_b, wa1, wa2,
                                               encA, ssA, snA, 0,
                                               deg_in, slot_cur, csc_pos, 0);
  decfw_kernel<<<B * V / DNV, 256, 0, stream>>>(encA, dec_w1, dec_b1, dual_w1, dual_b1,
                                                dual_w2, dual_b2, w2t, dec_b2, nbr_out,
                                                deg_out, csc_pos, fwe, meta, rssq, dv);
  flow_dual_kernel<<<B, 1024, 0, stream>>>(fwe, meta, rssq, dv, demands, nbr_out, deg_out,
                                           partial, done, (float*)d_out);
}

// Round 17
// 145.888 us; speedup vs baseline: 1.0216x; 1.0184x over previous
//
#include <hip/hip_runtime.h>
#include <math.h>

#define B 8
#define V 1024
#define E 32
#define H 4
#define CAP 64        // max out-degree capacity; E[deg]=17, P(deg>64) ~ 1e-21
#define MAXNNZ 20480  // nnz ~ 17390 +/- 128; +24 sigma headroom
#define ZBLK 128      // zero-role blocks in setup kernel

// XCD-aware decode: blockIdx round-robins across 8 XCDs on MI355X, and B==8.
// b = blockIdx & 7 pins each batch to one XCD -> per-XCD working set fits 4MB L2.

__device__ __forceinline__ float wave_sum(float v) {
  for (int o = 32; o > 0; o >>= 1) v += __shfl_xor(v, o);
  return v;
}
__device__ __forceinline__ float wave_max(float v) {
  for (int o = 32; o > 0; o >>= 1) v = fmaxf(v, __shfl_xor(v, o));
  return v;
}

// ---- L0: zero deg_in/slot_cur/done + precompute wa1/wa2 = gat_w @ a1/a2 ----
__global__ void zero_wa_kernel(int* __restrict__ deg_in, int* __restrict__ slot_cur,
                               unsigned* __restrict__ done, const float* __restrict__ gat_w,
                               const float* __restrict__ a1, const float* __restrict__ a2,
                               float* __restrict__ wa1, float* __restrict__ wa2) {
  int blk = blockIdx.x, tid = threadIdx.x;
  if (blk < 4) {
    deg_in[blk * 256 + tid] = 0;
  } else if (blk < 8) {
    slot_cur[(blk - 4) * 256 + tid] = 0;
  } else {
    if (tid == 0) *done = 0u;
    int h = tid >> 6, f = tid & 63;
    float s1 = 0.f, s2 = 0.f;
    const float* W = gat_w + h * 4096 + f * 64;
    for (int g = 0; g < 64; ++g) {
      float w = W[g];
      s1 += w * a1[h * 64 + g];
      s2 += w * a2[h * 64 + g];
    }
    wa1[h * 64 + f] = s1;
    wa2[h * 64 + f] = s2;
  }
}

// ---- L1: merged setup (64-thread blocks, role by blockIdx) ----
#define ENV 8
__global__ void setup_kernel(const float* __restrict__ adj, const float* __restrict__ demands,
                             const float* __restrict__ emb,
                             const float* __restrict__ ew1, const float* __restrict__ eb1,
                             const float* __restrict__ ew2, const float* __restrict__ eb2,
                             const float* __restrict__ dec_w2,
                             const float* __restrict__ wa1, const float* __restrict__ wa2,
                             int* __restrict__ nbr, int* __restrict__ deg,
                             int* __restrict__ deg_in, float* __restrict__ enc,
                             float* __restrict__ ss, float* __restrict__ sn,
                             float* __restrict__ w2t, float* __restrict__ fwe,
                             unsigned int* __restrict__ meta) {
  int blk = blockIdx.x;
  int j = threadIdx.x;  // 64
  if (blk < V) {
    int v = blk;
    int base = 0;
    for (int c = 0; c < V; c += 64) {
      float a = adj[v * V + c + j];
      unsigned long long m = __ballot(a > 0.5f);
      int pos = __popcll(m & ((1ull << j) - 1ull));
      if (a > 0.5f && base + pos < CAP) {
        nbr[v * CAP + base + pos] = c + j;
        atomicAdd(&deg_in[c + j], 1);
      }
      base += __popcll(m);
    }
    if (j == 0) deg[v] = (base < CAP) ? base : CAP;
  } else if (blk < 2 * V) {
    int eb = blk - V;
    int b = eb & 7;
    int v0 = (eb >> 3) * ENV;
    int bv0 = b * V + v0;
    __shared__ float xs[ENV][E + 1];
    __shared__ float hs[ENV][64];
#pragma unroll
    for (int n = 0; n < ENV; ++n) {
      if (j < E) xs[n][j] = emb[(v0 + n) * E + j];
      else if (j == E) xs[n][E] = demands[b * V + v0 + n];
    }
    __syncthreads();
    float h[ENV];
#pragma unroll
    for (int n = 0; n < ENV; ++n) h[n] = eb1[j];
    for (int i = 0; i < E + 1; ++i) {
      float wv = ew1[i * 64 + j];
#pragma unroll
      for (int n = 0; n < ENV; ++n) h[n] += xs[n][i] * wv;
    }
#pragma unroll
    for (int n = 0; n < ENV; ++n) hs[n][j] = fmaxf(h[n], 0.f);
    __syncthreads();
    float o[ENV];
#pragma unroll
    for (int n = 0; n < ENV; ++n) o[n] = eb2[j];
    for (int i = 0; i < 64; ++i) {
      float wv = ew2[i * 64 + j];
#pragma unroll
      for (int n = 0; n < ENV; ++n) o[n] += hs[n][i] * wv;
    }
#pragma unroll
    for (int n = 0; n < ENV; ++n) {
      o[n] = fmaxf(o[n], 0.f);
      enc[(bv0 + n) * 64 + j] = o[n];
    }
#pragma unroll
    for (int n = 0; n < ENV; ++n) {
#pragma unroll
      for (int hh = 0; hh < H; ++hh) {
        float v1 = wave_sum(o[n] * wa1[hh * 64 + j]);
        float v2 = wave_sum(o[n] * wa2[hh * 64 + j]);
        if (j == 0) {
          ss[(b * H + hh) * V + v0 + n] = v1;
          sn[(b * H + hh) * V + v0 + n] = v2;
        }
      }
    }
  } else if (blk < 3 * V) {
    int w = blk - 2 * V;
    w2t[w * 64 + j] = dec_w2[j * V + w];
  } else {
    int idx = (blk - 3 * V) * 64 + j;
    for (int i = idx; i < B * MAXNNZ; i += ZBLK * 64) fwe[i] = 0.f;
    for (int i = idx; i < MAXNNZ; i += ZBLK * 64) meta[i] = 0u;
  }
}

// ---- L2/L3: GAT layer (aggregate-then-project, 4-wide load batches) ----
#define GNV 8
__global__ __launch_bounds__(256) void gat2_kernel(
    const float* __restrict__ enc_in, const float* __restrict__ ss_in,
    const float* __restrict__ sn_in, const int* __restrict__ nbr,
    const int* __restrict__ deg, const float* __restrict__ gat_w,
    const float* __restrict__ gate_w, const float* __restrict__ gate_u,
    const float* __restrict__ gate_b, const float* __restrict__ wa1,
    const float* __restrict__ wa2, float* __restrict__ enc_out,
    float* __restrict__ ss_out, float* __restrict__ sn_out, int write_s,
    const int* __restrict__ deg_in, int* __restrict__ slot_cur,
    int* __restrict__ csc_pos, int* __restrict__ in_off_g, int do_csc) {
  int b = blockIdx.x & 7;
  int v0 = (blockIdx.x >> 3) * GNV;
  int tid = threadIdx.x;  // 256
  int wid = tid >> 6, lane = tid & 63;
  __shared__ float agg[GNV][H][64];   // 8 KB
  __shared__ float gpart[GNV][4][64]; // 8 KB
  __shared__ float nxts[GNV][64];     // 2 KB
  __shared__ float encs[GNV][64];     // 2 KB
  __shared__ int ioff[V];             // 4 KB (csc tail)
  const float* eb = enc_in + (size_t)b * V * 64;
  for (int i = tid; i < GNV * 64; i += 256) encs[i >> 6][i & 63] = eb[v0 * 64 + i];
  for (int n = wid; n < GNV; n += 4) {
    int v = v0 + n;
    int dvv = deg[v];
    int wk = (lane < dvv) ? nbr[v * CAP + lane] : 0;
    float c[H];
#pragma unroll
    for (int h = 0; h < H; ++h) {
      float x = ss_in[(b * H + h) * V + v] + sn_in[(b * H + h) * V + wk];
      x = (x > 0.f) ? x : 0.2f * x;  // leaky_relu 0.2
      if (lane >= dvv) x = -1e30f;
      float m = wave_max(x);
      float e = (lane < dvv) ? __expf(x - m) : 0.f;
      float s = wave_sum(e);
      c[h] = e / s;
    }
    float a0 = 0.f, a1v = 0.f, a2v = 0.f, a3v = 0.f;
    for (int k0 = 0; k0 < dvv; k0 += 4) {
      int r = dvv - k0;  // wave-uniform
      int w0 = __shfl(wk, k0 & 63);
      int w1 = __shfl(wk, (k0 + 1) & 63);
      int w2 = __shfl(wk, (k0 + 2) & 63);
      int w3 = __shfl(wk, (k0 + 3) & 63);
      float e0 = eb[w0 * 64 + lane];
      float e1 = (r > 1) ? eb[w1 * 64 + lane] : 0.f;
      float e2 = (r > 2) ? eb[w2 * 64 + lane] : 0.f;
      float e3 = (r > 3) ? eb[w3 * 64 + lane] : 0.f;
      a0 += __shfl(c[0], k0 & 63) * e0;
      a1v += __shfl(c[1], k0 & 63) * e0;
      a2v += __shfl(c[2], k0 & 63) * e0;
      a3v += __shfl(c[3], k0 & 63) * e0;
      if (r > 1) {
        a0 += __shfl(c[0], (k0 + 1) & 63) * e1;
        a1v += __shfl(c[1], (k0 + 1) & 63) * e1;
        a2v += __shfl(c[2], (k0 + 1) & 63) * e1;
        a3v += __shfl(c[3], (k0 + 1) & 63) * e1;
      }
      if (r > 2) {
        a0 += __shfl(c[0], (k0 + 2) & 63) * e2;
        a1v += __shfl(c[1], (k0 + 2) & 63) * e2;
        a2v += __shfl(c[2], (k0 + 2) & 63) * e2;
        a3v += __shfl(c[3], (k0 + 2) & 63) * e2;
      }
      if (r > 3) {
        a0 += __shfl(c[0], (k0 + 3) & 63) * e3;
        a1v += __shfl(c[1], (k0 + 3) & 63) * e3;
        a2v += __shfl(c[2], (k0 + 3) & 63) * e3;
        a3v += __shfl(c[3], (k0 + 3) & 63) * e3;
      }
    }
    agg[n][0][lane] = a0;
    agg[n][1][lane] = a1v;
    agg[n][2][lane] = a2v;
    agg[n][3][lane] = a3v;
  }
  __syncthreads();
  {
    const float* W = gat_w + wid * 4096;
    float hv[GNV];
#pragma unroll
    for (int n = 0; n < GNV; ++n) hv[n] = 0.f;
    for (int f = 0; f < 64; ++f) {
      float wf = W[f * 64 + lane];
#pragma unroll
      for (int n = 0; n < GNV; ++n) hv[n] += agg[n][wid][f] * wf;
    }
#pragma unroll
    for (int n = 0; n < GNV; ++n) gpart[n][wid][lane] = hv[n];
  }
  __syncthreads();
  for (int i = tid; i < GNV * 64; i += 256) {
    int n = i >> 6, g = i & 63;
    float s4 = gpart[n][0][g] + gpart[n][1][g] + gpart[n][2][g] + gpart[n][3][g];
    nxts[n][g] = fmaxf(0.25f * s4, 0.f);
  }
  __syncthreads();
  {
    float part[GNV];
#pragma unroll
    for (int n = 0; n < GNV; ++n) part[n] = 0.f;
    for (int f = wid * 16; f < wid * 16 + 16; ++f) {
      float gw = gate_w[f * 64 + lane], gu = gate_u[f * 64 + lane];
#pragma unroll
      for (int n = 0; n < GNV; ++n) part[n] += nxts[n][f] * gw + encs[n][f] * gu;
    }
    __syncthreads();
#pragma unroll
    for (int n = 0; n < GNV; ++n) gpart[n][wid][lane] = part[n];
  }
  __syncthreads();
  for (int i = tid; i < GNV * 64; i += 256) {
    int n = i >> 6, g = i & 63;
    float zs = gpart[n][0][g] + gpart[n][1][g] + gpart[n][2][g] + gpart[n][3][g] + gate_b[g];
    float z = 1.f / (1.f + __expf(-zs));
    float out = z * nxts[n][g] + (1.f - z) * encs[n][g];
    encs[n][g] = out;  // reuse as output buffer
    enc_out[((size_t)b * V + v0 + n) * 64 + g] = out;
  }
  if (write_s) {
    __syncthreads();
    float w1v = wa1[wid * 64 + lane], w2v = wa2[wid * 64 + lane];
#pragma unroll
    for (int n = 0; n < GNV; ++n) {
      float e = encs[n][lane];
      float ssv = wave_sum(e * w1v);
      float snv = wave_sum(e * w2v);
      if (lane == 0) {
        ss_out[(b * H + wid) * V + v0 + n] = ssv;
        sn_out[(b * H + wid) * V + v0 + n] = snv;
      }
    }
  }
  if (do_csc && b == 0) {  // exactly once per v-group
    __syncthreads();
    if (tid < 64) {
      int vals[16];
      int tot = 0;
#pragma unroll
      for (int i = 0; i < 16; ++i) {
        vals[i] = tot;
        tot += deg_in[tid * 16 + i];
      }
      int run = tot;
      for (int o = 1; o < 64; o <<= 1) {
        int u = __shfl_up(run, o);
        if (lane >= o) run += u;
      }
      int excl = run - tot;
#pragma unroll
      for (int i = 0; i < 16; ++i) ioff[tid * 16 + i] = excl + vals[i];
    }
    __syncthreads();
    if (v0 == 0) {  // one block materializes in_off for the flow kernels
      for (int i = tid; i < V; i += 256) in_off_g[i] = ioff[i];
      if (tid == 0) in_off_g[V] = ioff[V - 1] + deg_in[V - 1];
    }
    for (int n = wid; n < GNV; n += 4) {
      int v = v0 + n;
      if (lane < deg[v]) {
        int w = nbr[v * CAP + lane];
        csc_pos[v * CAP + lane] = ioff[w] + atomicAdd(&slot_cur[w], 1);
      }
    }
  }
}

// ---- L4: fused decoder+dual+flow-weights; also writes o1 = relu(-dem) ----
#define DNV 4
__global__ __launch_bounds__(256) void decfw_kernel(
    const float* __restrict__ enc, const float* __restrict__ dw1,
    const float* __restrict__ db1, const float* __restrict__ uw1,
    const float* __restrict__ ub1, const float* __restrict__ uw2,
    const float* __restrict__ ub2, const float* __restrict__ w2t,
    const float* __restrict__ dec_b2, const int* __restrict__ nbr,
    const int* __restrict__ deg, const int* __restrict__ csc_pos,
    const float* __restrict__ demands, float* __restrict__ fwe,
    unsigned int* __restrict__ meta, float* __restrict__ rssq,
    float* __restrict__ dvout, float* __restrict__ o1) {
  int b = blockIdx.x & 7;
  int v0 = (blockIdx.x >> 3) * DNV;
  int bv0 = b * V + v0;
  int tid = threadIdx.x;  // 256
  int wv = tid >> 6, j = tid & 63;
  __shared__ float es[DNV][64];
  __shared__ float hs[DNV][64];
  es[wv][j] = enc[(bv0 + wv) * 64 + j];
  __syncthreads();
  float hj = db1[j], uj = ub1[j];
  for (int f = 0; f < 64; ++f) {
    hj += es[wv][f] * dw1[f * 64 + j];
    uj += es[wv][f] * uw1[f * 64 + j];
  }
  hs[wv][j] = hj;  // NO relu: decoder is linear
  float sdv = wave_sum(uj * uw2[j]);
  if (j == 0) {
    dvout[bv0 + wv] = sdv + ub2[0];
    o1[bv0 + wv] = fmaxf(-demands[bv0 + wv], 0.f);  // o_1 for flow iterations
  }
  __syncthreads();
  int v = v0 + wv;
  int dvv = deg[v];
  int w = (j < dvv) ? nbr[v * CAP + j] : 0;
  const float4* wrow = (const float4*)(w2t + w * 64);
  const float4* hv4 = (const float4*)hs[wv];
  float d = 0.f;
#pragma unroll
  for (int f = 0; f < 16; ++f) {
    float4 wvv = wrow[f];
    float4 hv = hv4[f];  // LDS broadcast
    d += hv.x * wvv.x + hv.y * wvv.y + hv.z * wvv.z + hv.w * wvv.w;
  }
  d += dec_b2[w];
  float pp = d * d;
  float myp = (j < dvv) ? pp : -1e30f;
  float m = wave_max(myp);
  float e = (j < dvv) ? __expf(myp - m) : 0.f;
  float s = wave_sum(e);
  float coef = e / s;
  if (j < dvv) {
    int idx = csc_pos[v * CAP + j];
    fwe[(size_t)b * MAXNNZ + idx] = coef;
    meta[idx] = (unsigned)v | ((unsigned)w << 16);
  }
  float r = wave_sum(coef * coef);
  if (j == 0) rssq[bv0 + wv] = r;
}

// ---- L5 x8: one flow iteration, parallel over all (b, v): 128 blocks x 64 ----
// Each thread owns one dst node; its CSC edge range is contiguous.
__global__ __launch_bounds__(64) void flow_iter_kernel(
    const float* __restrict__ fwe, const unsigned* __restrict__ meta,
    const int* __restrict__ in_off, const float* __restrict__ demands,
    const float* __restrict__ o_cur, float* __restrict__ o_nxt) {
  int blk = blockIdx.x;  // 128 = 16 v-groups x 8 batches
  int b = blk & 7;
  int v = (blk >> 3) * 64 + threadIdx.x;
  float dem = demands[b * V + v];
  int e0 = in_off[v], e1 = in_off[v + 1];
  if (e1 > MAXNNZ) e1 = MAXNNZ;
  if (e0 > e1) e0 = e1;
  const float* fwb = fwe + (size_t)b * MAXNNZ;
  const float* ob = o_cur + b * V;
  float inflow = 0.f;
  int e = e0;
  for (; e + 3 < e1; e += 4) {  // 4-wide: batch the meta->o dependent chains
    unsigned m0 = meta[e], m1 = meta[e + 1], m2 = meta[e + 2], m3 = meta[e + 3];
    float f0 = fwb[e], f1 = fwb[e + 1], f2 = fwb[e + 2], f3 = fwb[e + 3];
    float o0 = ob[m0 & 0xFFFF], o1 = ob[m1 & 0xFFFF];
    float o2 = ob[m2 & 0xFFFF], o3 = ob[m3 & 0xFFFF];
    inflow += f0 * o0 + f1 * o1 + f2 * o2 + f3 * o3;
  }
  for (; e < e1; ++e) inflow += fwb[e] * ob[meta[e] & 0xFFFF];
  o_nxt[b * V + v] = fmaxf(inflow - dem, 0.f);
}

// ---- L6: final = iteration 9 (o9 -> o10) fused with flow cost + dual + out ----
__global__ __launch_bounds__(1024) void flow_final_kernel(
    const float* __restrict__ fwe, const unsigned* __restrict__ meta,
    const int* __restrict__ in_off, const float* __restrict__ rssq,
    const float* __restrict__ dv, const float* __restrict__ demands,
    const int* __restrict__ nbr_out, const int* __restrict__ deg_out,
    const float* __restrict__ o9, float* __restrict__ partial,
    unsigned* __restrict__ done, float* __restrict__ out) {
  int b = blockIdx.x;
  int v = threadIdx.x;  // 1024
  __shared__ float dvs[V];
  __shared__ float red[16];
  float dem = demands[b * V + v];
  dvs[v] = dv[b * V + v];
  __syncthreads();
  int e0 = in_off[v], e1 = in_off[v + 1];
  if (e1 > MAXNNZ) e1 = MAXNNZ;
  if (e0 > e1) e0 = e1;
  const float* fwb = fwe + (size_t)b * MAXNNZ;
  const float* ob = o9 + b * V;
  float inflow = 0.f;
  int e = e0;
  for (; e + 3 < e1; e += 4) {
    unsigned m0 = meta[e], m1 = meta[e + 1], m2 = meta[e + 2], m3 = meta[e + 3];
    float f0 = fwb[e], f1 = fwb[e + 1], f2 = fwb[e + 2], f3 = fwb[e + 3];
    float p0 = ob[m0 & 0xFFFF], p1 = ob[m1 & 0xFFFF];
    float p2 = ob[m2 & 0xFFFF], p3 = ob[m3 & 0xFFFF];
    inflow += f0 * p0 + f1 * p1 + f2 * p2 + f3 * p3;
  }
  for (; e < e1; ++e) inflow += fwb[e] * ob[meta[e] & 0xFFFF];
  float o10 = fmaxf(inflow - dem, 0.f);
  float local = o10 * o10 * rssq[b * V + v];
  // dual: 0.25*sum_edges relu(dv_v - dv_w)^2 + dv_v*dem_v (scalar R14 form)
  float dvv = dvs[v];
  int dout = deg_out[v];
  float acc = 0.f;
  for (int k = 0; k < dout; ++k) {
    float diff = dvv - dvs[nbr_out[v * CAP + k]];
    if (diff > 0.f) acc += diff * diff;
  }
  local += 0.25f * acc + dvv * dem;
  local = wave_sum(local);
  if ((v & 63) == 0) red[v >> 6] = local;
  __syncthreads();
  if (v < 16) {
    float r = red[v];
    for (int o2 = 8; o2 > 0; o2 >>= 1) r += __shfl_xor(r, o2, 16);
    if (v == 0) {
      __hip_atomic_store(&partial[b], r, __ATOMIC_RELEASE, __HIP_MEMORY_SCOPE_AGENT);
      unsigned old = __hip_atomic_fetch_add(done, 1u, __ATOMIC_ACQ_REL, __HIP_MEMORY_SCOPE_AGENT);
      if (old == B - 1) {  // last block: deterministic fixed-order sum
        float s = 0.f;
        for (int i = 0; i < B; ++i)
          s += __hip_atomic_load(&partial[i], __ATOMIC_ACQUIRE, __HIP_MEMORY_SCOPE_AGENT);
        out[0] = s * (1.0f / B);
      }
    }
  }
}

extern "C" void kernel_launch(void* const* d_in, const int* in_sizes, int n_in,
                              void* d_out, int out_size, void* d_ws, size_t ws_size,
                              hipStream_t stream) {
  const float* demands = (const float*)d_in[0];
  const float* emb     = (const float*)d_in[1];
  const float* adj     = (const float*)d_in[2];
  const float* enc_w1  = (const float*)d_in[3];
  const float* enc_b1  = (const float*)d_in[4];
  const float* enc_w2  = (const float*)d_in[5];
  const float* enc_b2  = (const float*)d_in[6];
  const float* gat_w   = (const float*)d_in[7];
  const float* gat_a1  = (const float*)d_in[8];
  const float* gat_a2  = (const float*)d_in[9];
  const float* gate_w  = (const float*)d_in[10];
  const float* gate_u  = (const float*)d_in[11];
  const float* gate_b  = (const float*)d_in[12];
  const float* dec_w1  = (const float*)d_in[13];
  const float* dec_b1  = (const float*)d_in[14];
  const float* dec_w2  = (const float*)d_in[15];
  const float* dec_b2  = (const float*)d_in[16];
  const float* dual_w1 = (const float*)d_in[17];
  const float* dual_b1 = (const float*)d_in[18];
  const float* dual_w2 = (const float*)d_in[19];
  const float* dual_b2 = (const float*)d_in[20];

  char* pz = (char*)d_ws;
  int* deg_in   = (int*)pz;                 // 4096 B (zeroed by zero_wa)
  int* slot_cur = (int*)(pz + 4096);        // 4096 B (zeroed by zero_wa)
  unsigned* done = (unsigned*)(pz + 8192);  // 4 B    (zeroed by zero_wa)
  char* p = pz + 8448;
  auto alloc = [&](size_t n) { void* r = (void*)p; p += (n + 255) & ~(size_t)255; return r; };
  int* nbr_out   = (int*)alloc((size_t)V * CAP * 4);
  int* deg_out   = (int*)alloc((size_t)V * 4);
  int* csc_pos   = (int*)alloc((size_t)V * CAP * 4);
  int* in_off    = (int*)alloc((size_t)(V + 1) * 4);
  float* fwe     = (float*)alloc((size_t)B * MAXNNZ * 4);
  unsigned int* meta = (unsigned int*)alloc((size_t)MAXNNZ * 4);
  float* w2t     = (float*)alloc((size_t)64 * V * 4);
  float* wa1     = (float*)alloc((size_t)H * 64 * 4);
  float* wa2     = (float*)alloc((size_t)H * 64 * 4);
  float* encA    = (float*)alloc((size_t)B * V * 64 * 4);
  float* encB    = (float*)alloc((size_t)B * V * 64 * 4);
  float* ssA     = (float*)alloc((size_t)B * H * V * 4);
  float* snA     = (float*)alloc((size_t)B * H * V * 4);
  float* ssB     = (float*)alloc((size_t)B * H * V * 4);
  float* snB     = (float*)alloc((size_t)B * H * V * 4);
  float* dv      = (float*)alloc((size_t)B * V * 4);
  float* rssq    = (float*)alloc((size_t)B * V * 4);
  float* oA      = (float*)alloc((size_t)B * V * 4);
  float* oB      = (float*)alloc((size_t)B * V * 4);
  float* partial = (float*)alloc((size_t)B * 4);

  zero_wa_kernel<<<9, 256, 0, stream>>>(deg_in, slot_cur, done, gat_w, gat_a1, gat_a2,
                                        wa1, wa2);
  setup_kernel<<<3 * V + ZBLK, 64, 0, stream>>>(
      adj, demands, emb, enc_w1, enc_b1, enc_w2, enc_b2, dec_w2, wa1, wa2,
      nbr_out, deg_out, deg_in, encA, ssA, snA, w2t, fwe, meta);
  gat2_kernel<<<B * V / GNV, 256, 0, stream>>>(encA, ssA, snA, nbr_out, deg_out, gat_w,
                                               gate_w, gate_u, gate_b, wa1, wa2,
                                               encB, ssB, snB, 1,
                                               deg_in, slot_cur, csc_pos, in_off, 1);
  gat2_kernel<<<B * V / GNV, 256, 0, stream>>>(encB, ssB, snB, nbr_out, deg_out, gat_w,
                                               gate_w, gate_u, gate_b, wa1, wa2,
                                               encA, ssA, snA, 0,
                                               deg_in, slot_cur, csc_pos, in_off, 0);
  decfw_kernel<<<B * V / DNV, 256, 0, stream>>>(encA, dec_w1, dec_b1, dual_w1, dual_b1,
                                                dual_w2, dual_b2, w2t, dec_b2, nbr_out,
                                                deg_out, csc_pos, demands, fwe, meta,
                                                rssq, dv, oA);
  // o1 in oA; 8 iterations o1->...->o9 (ping-pong), then final does o9->o10+costs
  float* cur = oA;
  float* nxt = oB;
  for (int it = 0; it < 8; ++it) {
    flow_iter_kernel<<<B * V / 64, 64, 0, stream>>>(fwe, meta, in_off, demands, cur, nxt);
    float* tmp = cur; cur = nxt; nxt = tmp;
  }
  flow_final_kernel<<<B, 1024, 0, stream>>>(fwe, meta, in_off, rssq, dv, demands,
                                            nbr_out, deg_out, cur, partial, done,
                                            (float*)d_out);
}